// Round 6
// baseline (176.361 us; speedup 1.0000x reference)
//
#include <hip/hip_runtime.h>

#define B_ 8
#define T_ 2048
#define C_ 1024
#define H_ 64

typedef __attribute__((ext_vector_type(8))) short short8;
typedef __attribute__((ext_vector_type(4))) float floatx4;
typedef __attribute__((ext_vector_type(4))) int intx4;

static __device__ __forceinline__ unsigned short f2bf(float f) {
  unsigned int u = __builtin_bit_cast(unsigned int, f);
  u += 0x7FFFu + ((u >> 16) & 1u);   // RNE
  return (unsigned short)(u >> 16);
}
static __device__ __forceinline__ unsigned short f2bf_t(float f) {   // truncate
  return (unsigned short)(__builtin_bit_cast(unsigned int, f) >> 16);
}
static __device__ __forceinline__ float bf2f(unsigned short u) {
  return __builtin_bit_cast(float, ((unsigned int)u) << 16);
}
static __device__ __forceinline__ unsigned int fbits(float f) {
  return __builtin_bit_cast(unsigned int, f);
}

typedef const __attribute__((address_space(1))) unsigned int* gp1_t;
typedef __attribute__((address_space(3))) unsigned int* lp3_t;
// async global->LDS, 16B per lane; LDS dst = wave-uniform base + lane*16
static __device__ __forceinline__ void gl_lds16(const void* g, void* l) {
  __builtin_amdgcn_global_load_lds((gp1_t)g, (lp3_t)l, 16, 0, 0);
}

// ---------------------------------------------------------------------------
// Kernel 0: W[1024][64] fp32 (q,k,v) -> Wt[192][1024] bf16 (n-major, k-contig)
// Softmax scale C^-0.5 and log2(e) folded into Wq rows.
// ---------------------------------------------------------------------------
__global__ __launch_bounds__(256) void conv_w(const float* __restrict__ wq,
    const float* __restrict__ wk, const float* __restrict__ wv,
    unsigned short* __restrict__ wt) {
  int idx = blockIdx.x * 256 + threadIdx.x;   // 49152 float4s total
  int mat = idx >> 14;
  int e = idx & 16383;
  int kk = e >> 4, c0 = (e & 15) * 4;
  const float* src = (mat == 0) ? wq : (mat == 1) ? wk : wv;
  float scale = (mat == 0) ? 0.03125f * 1.44269504088896340736f : 1.0f;
  float4 v = *(const float4*)&src[kk * H_ + c0];
  wt[(size_t)(mat * 64 + c0 + 0) * C_ + kk] = f2bf(v.x * scale);
  wt[(size_t)(mat * 64 + c0 + 1) * C_ + kk] = f2bf(v.y * scale);
  wt[(size_t)(mat * 64 + c0 + 2) * C_ + kk] = f2bf(v.z * scale);
  wt[(size_t)(mat * 64 + c0 + 3) * C_ + kk] = f2bf(v.w * scale);
}

// ---------------------------------------------------------------------------
// Kernel 1: QKV projection, async-LDS GEMM (unchanged from round 5).
// 32-row tiles, grid 512, BK=64, double-buffered, XOR source swizzle.
// v output is written TRANSPOSED: vT[b*64+h][t].
// ---------------------------------------------------------------------------
__global__ __launch_bounds__(256) void qkv_proj(
    const float* __restrict__ x, const unsigned short* __restrict__ wt,
    unsigned short* __restrict__ qo, unsigned short* __restrict__ ko,
    unsigned short* __restrict__ vT) {
  __shared__ float XL[2][2048];            // 2 x 32x64 fp32 = 16 KB
  __shared__ unsigned short WL[2][12288];  // 2 x 192x64 bf16 = 48 KB
  int tid = threadIdx.x;
  int wave = tid >> 6, lane = tid & 63;
  int lane4 = lane & 15, quad = lane >> 4;
  int m0 = blockIdx.x * 32;

  floatx4 acc[2][3];
#pragma unroll
  for (int mt = 0; mt < 2; ++mt)
#pragma unroll
    for (int nt = 0; nt < 3; ++nt) acc[mt][nt] = (floatx4)0.0f;

#pragma unroll
  for (int j = 0; j < 2; ++j) {
    int p = (wave * 2 + j) * 64 + lane;
    int r = p >> 4, pc = p & 15;
    int cl = (pc & 8) | ((pc ^ (r & 7)) & 7);
    gl_lds16(&x[(size_t)(m0 + r) * C_ + cl * 4], &XL[0][(wave * 2 + j) * 256]);
  }
#pragma unroll
  for (int j = 0; j < 6; ++j) {
    int p = (wave * 6 + j) * 64 + lane;
    int r = p >> 3, pc = p & 7;
    int cl = pc ^ (r & 7);
    gl_lds16(&wt[(size_t)r * C_ + cl * 8], &WL[0][(wave * 6 + j) * 512]);
  }
  __syncthreads();

  for (int kt = 0; kt < 16; ++kt) {
    int buf = kt & 1;
    if (kt < 15) {
      int k0 = (kt + 1) * 64;
#pragma unroll
      for (int j = 0; j < 2; ++j) {
        int p = (wave * 2 + j) * 64 + lane;
        int r = p >> 4, pc = p & 15;
        int cl = (pc & 8) | ((pc ^ (r & 7)) & 7);
        gl_lds16(&x[(size_t)(m0 + r) * C_ + k0 + cl * 4], &XL[buf ^ 1][(wave * 2 + j) * 256]);
      }
#pragma unroll
      for (int j = 0; j < 6; ++j) {
        int p = (wave * 6 + j) * 64 + lane;
        int r = p >> 3, pc = p & 7;
        int cl = pc ^ (r & 7);
        gl_lds16(&wt[(size_t)r * C_ + k0 + cl * 8], &WL[buf ^ 1][(wave * 6 + j) * 512]);
      }
    }

#pragma unroll
    for (int ks = 0; ks < 2; ++ks) {
      short8 a[2];
#pragma unroll
      for (int mt = 0; mt < 2; ++mt) {
        int r = mt * 16 + lane4;
        int cl0 = ks * 8 + quad * 2;
        int pc0 = (cl0 & 8) | ((cl0 ^ (r & 7)) & 7);
        int pc1 = ((cl0 + 1) & 8) | (((cl0 + 1) ^ (r & 7)) & 7);
        float4 f0 = *(const float4*)&XL[buf][r * 64 + pc0 * 4];
        float4 f1 = *(const float4*)&XL[buf][r * 64 + pc1 * 4];
        intx4 pk;
        pk[0] = (int)__builtin_amdgcn_perm(fbits(f0.y), fbits(f0.x), 0x07060302u);
        pk[1] = (int)__builtin_amdgcn_perm(fbits(f0.w), fbits(f0.z), 0x07060302u);
        pk[2] = (int)__builtin_amdgcn_perm(fbits(f1.y), fbits(f1.x), 0x07060302u);
        pk[3] = (int)__builtin_amdgcn_perm(fbits(f1.w), fbits(f1.z), 0x07060302u);
        a[mt] = __builtin_bit_cast(short8, pk);
      }
      short8 b[3];
#pragma unroll
      for (int nt = 0; nt < 3; ++nt) {
        int r = (wave * 3 + nt) * 16 + lane4;
        int cl = ks * 4 + quad;
        int pc = cl ^ (r & 7);
        b[nt] = *(const short8*)&WL[buf][r * 64 + pc * 8];
      }
#pragma unroll
      for (int mt = 0; mt < 2; ++mt)
#pragma unroll
        for (int nt = 0; nt < 3; ++nt)
          acc[mt][nt] = __builtin_amdgcn_mfma_f32_16x16x32_bf16(a[mt], b[nt], acc[mt][nt], 0, 0, 0);
    }
    __syncthreads();
  }

  unsigned short* VTB = (unsigned short*)&XL[0][0];   // [64 h][40] bf16
#pragma unroll
  for (int mt = 0; mt < 2; ++mt)
#pragma unroll
    for (int nt = 0; nt < 3; ++nt) {
      int n = wave * 48 + nt * 16 + lane4;
#pragma unroll
      for (int rr = 0; rr < 4; ++rr) {
        unsigned short val = f2bf(acc[mt][nt][rr]);
        int lrow = mt * 16 + quad * 4 + rr;
        if (n < 64)       qo[(size_t)(m0 + lrow) * H_ + n] = val;
        else if (n < 128) ko[(size_t)(m0 + lrow) * H_ + n - 64] = val;
        else              VTB[(n - 128) * 40 + lrow] = val;
      }
    }
  __syncthreads();
  {
    int h = tid >> 2, ch = tid & 3;
    int batch = m0 >> 11, t0 = m0 & 2047;
    uint4 v0 = *(const uint4*)&VTB[h * 40 + ch * 8];
    *(uint4*)&vT[(size_t)(batch * 64 + h) * T_ + t0 + ch * 8] = v0;
  }
}

// ---------------------------------------------------------------------------
// Kernel 2: causal flash attention, BARRIER-FREE. Split-4, fixed-max softmax
// (m=8, base-2 scale folded into Wq). Each wave owns 16 q-rows and loads its
// own K/V fragments DIRECTLY global->VGPR (L2-resident; 16 independent b128
// loads per tile = real MLP). No LDS staging, no __syncthreads anywhere ->
// waves never wait on each other; LDS = 9 KB (P round-trip only, same-wave,
// lgkmcnt-ordered).
// ---------------------------------------------------------------------------
__global__ __launch_bounds__(256) void attn(
    const unsigned short* __restrict__ qi, const unsigned short* __restrict__ ki,
    const unsigned short* __restrict__ vT, unsigned short* __restrict__ Op,
    float* __restrict__ lsum) {
  __shared__ unsigned short PL[4][16][72];   // per-wave P round-trip (bf16)

  int tid = threadIdx.x;
  int wave = tid >> 6, lane = tid & 63;
  int lane4 = lane & 15, quad = lane >> 4;
  int qt = blockIdx.x, b = blockIdx.y, split = blockIdx.z;
  int qb = qt * 64;
  int base = b * T_;

  int ntile = qt + 1;
  int sBeg = (split * ntile) >> 2;
  int sEnd = ((split + 1) * ntile) >> 2;

  // Q A-fragments: A[m=lane4][k=quad*8+j]
  short8 aq[2];
#pragma unroll
  for (int ks = 0; ks < 2; ++ks)
    aq[ks] = *(const short8*)&qi[(size_t)(base + qb + wave * 16 + lane4) * H_ + ks * 32 + quad * 8];

  float lrow[4];
  floatx4 o[4];
#pragma unroll
  for (int r = 0; r < 4; ++r) lrow[r] = 0.0f;
#pragma unroll
  for (int nt = 0; nt < 4; ++nt) o[nt] = (floatx4)0.0f;

  // per-wave load bases
  const unsigned short* kbase = &ki[(size_t)(base + lane4) * H_ + quad * 8];
  const unsigned short* vbase = &vT[((size_t)b * H_ + lane4) * T_ + quad * 8];

  for (int st = sBeg; st < sEnd; ++st) {
    int s0 = st * 64;
    // K B-frags: B[n=s=ct*16+lane4][k=h=ks*32+quad*8+j] -- coalesced 2KB/inst
    short8 bk[2][4];
#pragma unroll
    for (int ks = 0; ks < 2; ++ks)
#pragma unroll
      for (int ct = 0; ct < 4; ++ct)
        bk[ks][ct] = *(const short8*)&kbase[(size_t)(s0 + ct * 16) * H_ + ks * 32];
    // V B-frags: B[n=h=nt*16+lane4][k=s=ks*32+quad*8+j] from vT[h][s]
    short8 bv[2][4];
#pragma unroll
    for (int ks = 0; ks < 2; ++ks)
#pragma unroll
      for (int nt = 0; nt < 4; ++nt)
        bv[ks][nt] = *(const short8*)&vbase[(size_t)(nt * 16) * T_ + s0 + ks * 32];

    // S = Q K^T  (16 x 64 per wave)
    floatx4 sacc[4];
#pragma unroll
    for (int ct = 0; ct < 4; ++ct) sacc[ct] = (floatx4)0.0f;
#pragma unroll
    for (int ks = 0; ks < 2; ++ks)
#pragma unroll
      for (int ct = 0; ct < 4; ++ct)
        sacc[ct] = __builtin_amdgcn_mfma_f32_16x16x32_bf16(aq[ks], bk[ks][ct], sacc[ct], 0, 0, 0);

    if (st == qt) {   // diagonal tile mask
#pragma unroll
      for (int ct = 0; ct < 4; ++ct)
#pragma unroll
        for (int r = 0; r < 4; ++r) {
          int qrow = wave * 16 + quad * 4 + r;
          int scol = ct * 16 + lane4;
          if (scol > qrow) sacc[ct][r] = -3.0e38f;
        }
    }

    // fixed-max softmax: p = exp2(s - 8); truncating bf16 pack
#pragma unroll
    for (int ct = 0; ct < 4; ++ct)
#pragma unroll
      for (int r = 0; r < 4; ++r) {
        float p = exp2f(sacc[ct][r] - 8.0f);
        lrow[r] += p;
        PL[wave][quad * 4 + r][ct * 16 + lane4] = f2bf_t(p);
      }

    // O += P V  (PL write->read same-wave; lgkmcnt orders it)
#pragma unroll
    for (int ks = 0; ks < 2; ++ks) {
      short8 pa = *(const short8*)&PL[wave][lane4][ks * 32 + quad * 8];
#pragma unroll
      for (int nt = 0; nt < 4; ++nt)
        o[nt] = __builtin_amdgcn_mfma_f32_16x16x32_bf16(pa, bv[ks][nt], o[nt], 0, 0, 0);
    }
  }

  // epilogue: l-reduce across the 16 lanes of each quad-group
#pragma unroll
  for (int off = 1; off < 16; off <<= 1)
#pragma unroll
    for (int r = 0; r < 4; ++r) lrow[r] += __shfl_xor(lrow[r], off);

  size_t pbase = (((size_t)split * 8 + b) * 32 + qt) * 64;
#pragma unroll
  for (int r = 0; r < 4; ++r) {
    int row = wave * 16 + quad * 4 + r;
#pragma unroll
    for (int nt = 0; nt < 4; ++nt)
      Op[(pbase + row) * 64 + nt * 16 + lane4] = f2bf(o[nt][r]);
    if (lane4 == 0) lsum[pbase + row] = lrow[r];
  }
}

// ---------------------------------------------------------------------------
// Kernel 3: merge the 4 key-range splits: out = sum(O_i) / sum(l_i).
// ---------------------------------------------------------------------------
__global__ __launch_bounds__(256) void merge_splits(
    const unsigned short* __restrict__ Op, const float* __restrict__ lsum,
    float* __restrict__ out) {
  int idx = blockIdx.x * 256 + threadIdx.x;   // 262144 float4 outputs
  int row = idx >> 4;
  int h4 = (idx & 15) * 4;
  int b = row >> 11, t = row & 2047;
  int qt = t >> 6, r = t & 63;
  float O0 = 0.f, O1 = 0.f, O2 = 0.f, O3 = 0.f, l = 0.f;
#pragma unroll
  for (int s = 0; s < 4; ++s) {
    size_t p = (((size_t)s * 8 + b) * 32 + qt) * 64 + r;
    l += lsum[p];
    ushort4 ov = *(const ushort4*)&Op[p * 64 + h4];
    O0 += bf2f(ov.x); O1 += bf2f(ov.y); O2 += bf2f(ov.z); O3 += bf2f(ov.w);
  }
  float inv = 1.0f / l;
  float4 res = make_float4(O0 * inv, O1 * inv, O2 * inv, O3 * inv);
  *(float4*)&out[(size_t)row * H_ + h4] = res;
}

extern "C" void kernel_launch(void* const* d_in, const int* in_sizes, int n_in,
                              void* d_out, int out_size, void* d_ws, size_t ws_size,
                              hipStream_t stream) {
  const float* x  = (const float*)d_in[0];
  const float* wq = (const float*)d_in[1];
  const float* wk = (const float*)d_in[2];
  const float* wv = (const float*)d_in[3];
  float* out = (float*)d_out;

  char* ws = (char*)d_ws;
  unsigned short* wt = (unsigned short*)ws;                    // 393216 B
  unsigned short* qb = (unsigned short*)(ws + 393216);         // 2097152 B
  unsigned short* kb = (unsigned short*)(ws + 2490368);        // 2097152 B
  unsigned short* vt = (unsigned short*)(ws + 4587520);        // 2097152 B (transposed)
  unsigned short* Op = (unsigned short*)(ws + 6684672);        // 8388608 B (4 splits)
  float*          ls = (float*)(ws + 15073280);                // 262144 B (total 15335424)

  conv_w<<<192, 256, 0, stream>>>(wq, wk, wv, wt);
  qkv_proj<<<512, 256, 0, stream>>>(x, wt, qb, kb, vt);
  attn<<<dim3(32, 8, 4), 256, 0, stream>>>(qb, kb, vt, Op, ls);
  merge_splits<<<1024, 256, 0, stream>>>(Op, ls, out);
}

// Round 7
// 137.387 us; speedup vs baseline: 1.2837x; 1.2837x over previous
//
#include <hip/hip_runtime.h>

#define B_ 8
#define T_ 2048
#define C_ 1024
#define H_ 64

typedef __attribute__((ext_vector_type(8))) short short8;
typedef __attribute__((ext_vector_type(4))) float floatx4;
typedef __attribute__((ext_vector_type(4))) int intx4;

static __device__ __forceinline__ unsigned short f2bf(float f) {
  unsigned int u = __builtin_bit_cast(unsigned int, f);
  u += 0x7FFFu + ((u >> 16) & 1u);   // RNE
  return (unsigned short)(u >> 16);
}
static __device__ __forceinline__ unsigned short f2bf_t(float f) {   // truncate
  return (unsigned short)(__builtin_bit_cast(unsigned int, f) >> 16);
}
static __device__ __forceinline__ float bf2f(unsigned short u) {
  return __builtin_bit_cast(float, ((unsigned int)u) << 16);
}
static __device__ __forceinline__ unsigned int fbits(float f) {
  return __builtin_bit_cast(unsigned int, f);
}

typedef const __attribute__((address_space(1))) unsigned int* gp1_t;
typedef __attribute__((address_space(3))) unsigned int* lp3_t;
static __device__ __forceinline__ void gl_lds16(const void* g, void* l) {
  __builtin_amdgcn_global_load_lds((gp1_t)g, (lp3_t)l, 16, 0, 0);
}

// ---------------------------------------------------------------------------
// Kernel 0: W fp32 -> Wf FRAGMENT-READY bf16.
// Chunk c = ((kt*2+ks)*12 + ng)*64 + lane holds 8 bf16:
//   element j = W[k][n], n = ng*16 + (lane&15), k = kt*64 + ks*32 + (lane>>4)*8 + j
// so qkv's B-fragment load is one contiguous b128 at (chunkbase + lane*16).
// Softmax scale C^-0.5 * log2(e) folded into Wq columns.
// ---------------------------------------------------------------------------
__global__ __launch_bounds__(256) void conv_w(const float* __restrict__ wq,
    const float* __restrict__ wk, const float* __restrict__ wv,
    unsigned short* __restrict__ wf) {
  int c = blockIdx.x * 256 + threadIdx.x;   // 24576 chunks
  int lane = c & 63;
  int t = c >> 6;
  int ng = t % 12;
  int kk = t / 12;                           // kt*2+ks, 0..31
  int k0 = kk * 32 + (lane >> 4) * 8;
  int n = ng * 16 + (lane & 15);
  const float* src;
  int col;
  float scale = 1.0f;
  if (n < 64)       { src = wq; col = n;       scale = 0.03125f * 1.44269504088896340736f; }
  else if (n < 128) { src = wk; col = n - 64;  }
  else              { src = wv; col = n - 128; }
  unsigned short o[8];
#pragma unroll
  for (int j = 0; j < 8; ++j) o[j] = f2bf(src[(size_t)(k0 + j) * H_ + col] * scale);
  *(uint4*)&wf[(size_t)c * 8] = *(const uint4*)o;
}

// ---------------------------------------------------------------------------
// Kernel 1: QKV projection. Grid 512 (32-row tiles), 4 waves, BK=64.
// x: async-LDS double-buffered (XOR source swizzle), 16 KB LDS total.
// W: DIRECT fragment loads from Wf (contiguous 1 KB bursts, L2-resident) --
// no W staging, so the per-tile barrier drains only 2 tiny x-loads/wave.
// Epilogue emits q direct and K/V in FRAGMENT-READY layouts Kf/Vf:
//   Kf chunk (((b*32+st)*2+ks)*4+ct)*64+lane : elem j = K[st*64+ct*16+(lane&15)][ks*32+(lane>>4)*8+j]
//   Vf chunk (((b*32+st)*2+ks)*4+nt)*64+lane : elem j = V[st*64+ks*32+(lane>>4)*8+j][nt*16+(lane&15)]
// ---------------------------------------------------------------------------
__global__ __launch_bounds__(256) void qkv_proj(
    const float* __restrict__ x, const unsigned short* __restrict__ wf,
    unsigned short* __restrict__ qo, unsigned short* __restrict__ kf,
    unsigned short* __restrict__ vf) {
  __shared__ float XL[2][2048];            // 2 x 32x64 fp32 = 16 KB
  int tid = threadIdx.x;
  int wave = tid >> 6, lane = tid & 63;
  int lane4 = lane & 15, quad = lane >> 4;
  int m0 = blockIdx.x * 32;

  floatx4 acc[2][3];
#pragma unroll
  for (int mt = 0; mt < 2; ++mt)
#pragma unroll
    for (int nt = 0; nt < 3; ++nt) acc[mt][nt] = (floatx4)0.0f;

#pragma unroll
  for (int j = 0; j < 2; ++j) {
    int p = (wave * 2 + j) * 64 + lane;
    int r = p >> 4, pc = p & 15;
    int cl = (pc & 8) | ((pc ^ (r & 7)) & 7);
    gl_lds16(&x[(size_t)(m0 + r) * C_ + cl * 4], &XL[0][(wave * 2 + j) * 256]);
  }
  __syncthreads();

  for (int kt = 0; kt < 16; ++kt) {
    int buf = kt & 1;
    if (kt < 15) {
      int k0 = (kt + 1) * 64;
#pragma unroll
      for (int j = 0; j < 2; ++j) {
        int p = (wave * 2 + j) * 64 + lane;
        int r = p >> 4, pc = p & 15;
        int cl = (pc & 8) | ((pc ^ (r & 7)) & 7);
        gl_lds16(&x[(size_t)(m0 + r) * C_ + k0 + cl * 4], &XL[buf ^ 1][(wave * 2 + j) * 256]);
      }
    }

#pragma unroll
    for (int ks = 0; ks < 2; ++ks) {
      short8 b[3];
#pragma unroll
      for (int nt = 0; nt < 3; ++nt)
        b[nt] = *(const short8*)&wf[(size_t)(((kt * 2 + ks) * 12) + wave * 3 + nt) * 512 + lane * 8];
      short8 a[2];
#pragma unroll
      for (int mt = 0; mt < 2; ++mt) {
        int r = mt * 16 + lane4;
        int cl0 = ks * 8 + quad * 2;
        int pc0 = (cl0 & 8) | ((cl0 ^ (r & 7)) & 7);
        int pc1 = ((cl0 + 1) & 8) | (((cl0 + 1) ^ (r & 7)) & 7);
        float4 f0 = *(const float4*)&XL[buf][r * 64 + pc0 * 4];
        float4 f1 = *(const float4*)&XL[buf][r * 64 + pc1 * 4];
        intx4 pk;
        pk[0] = (int)__builtin_amdgcn_perm(fbits(f0.y), fbits(f0.x), 0x07060302u);
        pk[1] = (int)__builtin_amdgcn_perm(fbits(f0.w), fbits(f0.z), 0x07060302u);
        pk[2] = (int)__builtin_amdgcn_perm(fbits(f1.y), fbits(f1.x), 0x07060302u);
        pk[3] = (int)__builtin_amdgcn_perm(fbits(f1.w), fbits(f1.z), 0x07060302u);
        a[mt] = __builtin_bit_cast(short8, pk);
      }
#pragma unroll
      for (int mt = 0; mt < 2; ++mt)
#pragma unroll
        for (int nt = 0; nt < 3; ++nt)
          acc[mt][nt] = __builtin_amdgcn_mfma_f32_16x16x32_bf16(a[mt], b[nt], acc[mt][nt], 0, 0, 0);
    }
    __syncthreads();
  }

  // ---- epilogue: q direct; K,V via LDS into fragment-ready layouts ----
  unsigned short* VTB = (unsigned short*)&XL[0][0];   // [64 h][40] bf16 (V^T)
  unsigned short* KB  = VTB + 5120;                   // [32 t][72] bf16
#pragma unroll
  for (int mt = 0; mt < 2; ++mt)
#pragma unroll
    for (int nt = 0; nt < 3; ++nt) {
      int n = wave * 48 + nt * 16 + lane4;
#pragma unroll
      for (int rr = 0; rr < 4; ++rr) {
        unsigned short val = f2bf(acc[mt][nt][rr]);
        int lrow = mt * 16 + quad * 4 + rr;
        if (n < 64)       qo[(size_t)(m0 + lrow) * H_ + n] = val;
        else if (n < 128) KB[lrow * 72 + (n - 64)] = val;
        else              VTB[(n - 128) * 40 + lrow] = val;
      }
    }
  __syncthreads();
  {
    int bb = m0 >> 11, t0 = m0 & 2047;
    int st = t0 >> 6, off = t0 & 63;
    // K: 256 chunks (ks x ctl x 64 lanes)
    int ks = tid >> 7, ctl = (tid >> 6) & 1, ln = tid & 63;
    int ct = (off >> 4) + ctl;
    int tl = ctl * 16 + (ln & 15);
    int h0 = ks * 32 + (ln >> 4) * 8;
    uint4 kd = *(const uint4*)&KB[tl * 72 + h0];
    *(uint4*)&kf[((size_t)((bb * 32 + st) * 2 + ks) * 4 + ct) * 512 + ln * 8] = kd;
    // V: 256 chunks (nt x 64 lanes), ks fixed = off>>5
    int nt = tid >> 6, l4 = tid & 15, qs = (tid >> 4) & 3;
    int ksv = off >> 5;
    uint4 vd = *(const uint4*)&VTB[(nt * 16 + l4) * 40 + qs * 8];
    *(uint4*)&vf[((size_t)((bb * 32 + st) * 2 + ksv) * 4 + nt) * 512 + (tid & 63) * 8] = vd;
  }
}

// ---------------------------------------------------------------------------
// Kernel 2: causal flash attention, barrier-free, split-4, fixed-max softmax
// (m=8, base-2 scale folded into Wq). K/V loaded from FRAGMENT-READY Kf/Vf:
// 16 contiguous-1KB b128 bursts per tile (L2-resident, no channel camping).
// Largest-work-first: qt = 31 - blockIdx.x. LDS = 9 KB (P round-trip only).
// ---------------------------------------------------------------------------
__global__ __launch_bounds__(256) void attn(
    const unsigned short* __restrict__ qi, const unsigned short* __restrict__ Kf,
    const unsigned short* __restrict__ Vf, unsigned short* __restrict__ Op,
    float* __restrict__ lsum) {
  __shared__ unsigned short PL[4][16][72];

  int tid = threadIdx.x;
  int wave = tid >> 6, lane = tid & 63;
  int lane4 = lane & 15, quad = lane >> 4;
  int qt = 31 - (int)blockIdx.x;   // biggest blocks dispatch first
  int b = blockIdx.y, split = blockIdx.z;
  int qb = qt * 64;
  int base = b * T_;

  int ntile = qt + 1;
  int sBeg = (split * ntile) >> 2;
  int sEnd = ((split + 1) * ntile) >> 2;

  short8 aq[2];
#pragma unroll
  for (int ks = 0; ks < 2; ++ks)
    aq[ks] = *(const short8*)&qi[(size_t)(base + qb + wave * 16 + lane4) * H_ + ks * 32 + quad * 8];

  float lrow[4];
  floatx4 o[4];
#pragma unroll
  for (int r = 0; r < 4; ++r) lrow[r] = 0.0f;
#pragma unroll
  for (int nt = 0; nt < 4; ++nt) o[nt] = (floatx4)0.0f;

  for (int st = sBeg; st < sEnd; ++st) {
    size_t tb = (size_t)(b * 32 + st) * 8;   // 8 chunk-groups of 512 shorts
    short8 bk[2][4], bv[2][4];
#pragma unroll
    for (int ks = 0; ks < 2; ++ks)
#pragma unroll
      for (int ct = 0; ct < 4; ++ct)
        bk[ks][ct] = *(const short8*)&Kf[(tb + ks * 4 + ct) * 512 + lane * 8];
#pragma unroll
    for (int ks = 0; ks < 2; ++ks)
#pragma unroll
      for (int nt = 0; nt < 4; ++nt)
        bv[ks][nt] = *(const short8*)&Vf[(tb + ks * 4 + nt) * 512 + lane * 8];

    floatx4 sacc[4];
#pragma unroll
    for (int ct = 0; ct < 4; ++ct) sacc[ct] = (floatx4)0.0f;
#pragma unroll
    for (int ks = 0; ks < 2; ++ks)
#pragma unroll
      for (int ct = 0; ct < 4; ++ct)
        sacc[ct] = __builtin_amdgcn_mfma_f32_16x16x32_bf16(aq[ks], bk[ks][ct], sacc[ct], 0, 0, 0);

    if (st == qt) {   // diagonal tile mask
#pragma unroll
      for (int ct = 0; ct < 4; ++ct)
#pragma unroll
        for (int r = 0; r < 4; ++r) {
          int qrow = wave * 16 + quad * 4 + r;
          int scol = ct * 16 + lane4;
          if (scol > qrow) sacc[ct][r] = -3.0e38f;
        }
    }

    // fixed-max softmax: p = exp2(s - 8)
#pragma unroll
    for (int ct = 0; ct < 4; ++ct)
#pragma unroll
      for (int r = 0; r < 4; ++r) {
        float p = exp2f(sacc[ct][r] - 8.0f);
        lrow[r] += p;
        PL[wave][quad * 4 + r][ct * 16 + lane4] = f2bf_t(p);
      }

    // O += P V  (PL write->read same-wave; lgkmcnt orders it)
#pragma unroll
    for (int ks = 0; ks < 2; ++ks) {
      short8 pa = *(const short8*)&PL[wave][lane4][ks * 32 + quad * 8];
#pragma unroll
      for (int nt = 0; nt < 4; ++nt)
        o[nt] = __builtin_amdgcn_mfma_f32_16x16x32_bf16(pa, bv[ks][nt], o[nt], 0, 0, 0);
    }
  }

  // epilogue: l-reduce across the 16 lanes of each quad-group
#pragma unroll
  for (int off = 1; off < 16; off <<= 1)
#pragma unroll
    for (int r = 0; r < 4; ++r) lrow[r] += __shfl_xor(lrow[r], off);

  size_t pbase = (((size_t)split * 8 + b) * 32 + qt) * 64;
#pragma unroll
  for (int r = 0; r < 4; ++r) {
    int row = wave * 16 + quad * 4 + r;
#pragma unroll
    for (int nt = 0; nt < 4; ++nt)
      Op[(pbase + row) * 64 + nt * 16 + lane4] = f2bf(o[nt][r]);
    if (lane4 == 0) lsum[pbase + row] = lrow[r];
  }
}

// ---------------------------------------------------------------------------
// Kernel 3: merge the 4 key-range splits: out = sum(O_i) / sum(l_i).
// ---------------------------------------------------------------------------
__global__ __launch_bounds__(256) void merge_splits(
    const unsigned short* __restrict__ Op, const float* __restrict__ lsum,
    float* __restrict__ out) {
  int idx = blockIdx.x * 256 + threadIdx.x;
  int row = idx >> 4;
  int h4 = (idx & 15) * 4;
  int b = row >> 11, t = row & 2047;
  int qt = t >> 6, r = t & 63;
  float O0 = 0.f, O1 = 0.f, O2 = 0.f, O3 = 0.f, l = 0.f;
#pragma unroll
  for (int s = 0; s < 4; ++s) {
    size_t p = (((size_t)s * 8 + b) * 32 + qt) * 64 + r;
    l += lsum[p];
    ushort4 ov = *(const ushort4*)&Op[p * 64 + h4];
    O0 += bf2f(ov.x); O1 += bf2f(ov.y); O2 += bf2f(ov.z); O3 += bf2f(ov.w);
  }
  float inv = 1.0f / l;
  float4 res = make_float4(O0 * inv, O1 * inv, O2 * inv, O3 * inv);
  *(float4*)&out[(size_t)row * H_ + h4] = res;
}

extern "C" void kernel_launch(void* const* d_in, const int* in_sizes, int n_in,
                              void* d_out, int out_size, void* d_ws, size_t ws_size,
                              hipStream_t stream) {
  const float* x  = (const float*)d_in[0];
  const float* wq = (const float*)d_in[1];
  const float* wk = (const float*)d_in[2];
  const float* wv = (const float*)d_in[3];
  float* out = (float*)d_out;

  char* ws = (char*)d_ws;
  unsigned short* wf = (unsigned short*)ws;                    // 393216 B
  unsigned short* qb = (unsigned short*)(ws + 393216);         // 2097152 B
  unsigned short* kf = (unsigned short*)(ws + 2490368);        // 2097152 B (frag-ready)
  unsigned short* vf = (unsigned short*)(ws + 4587520);        // 2097152 B (frag-ready)
  unsigned short* Op = (unsigned short*)(ws + 6684672);        // 8388608 B (4 splits)
  float*          ls = (float*)(ws + 15073280);                // 262144 B (total 15335424)

  conv_w<<<96, 256, 0, stream>>>(wq, wk, wv, wf);
  qkv_proj<<<512, 256, 0, stream>>>(x, wf, qb, kf, vf);
  attn<<<dim3(32, 8, 4), 256, 0, stream>>>(qb, kf, vf, Op, ls);
  merge_splits<<<1024, 256, 0, stream>>>(Op, ls, out);
}

// Round 8
// 135.006 us; speedup vs baseline: 1.3063x; 1.0176x over previous
//
#include <hip/hip_runtime.h>

#define B_ 8
#define T_ 2048
#define C_ 1024
#define H_ 64

typedef __attribute__((ext_vector_type(8))) short short8;
typedef __attribute__((ext_vector_type(4))) float floatx4;
typedef __attribute__((ext_vector_type(4))) int intx4;

static __device__ __forceinline__ unsigned short f2bf(float f) {
  unsigned int u = __builtin_bit_cast(unsigned int, f);
  u += 0x7FFFu + ((u >> 16) & 1u);   // RNE
  return (unsigned short)(u >> 16);
}
static __device__ __forceinline__ unsigned short f2bf_t(float f) {   // truncate
  return (unsigned short)(__builtin_bit_cast(unsigned int, f) >> 16);
}
static __device__ __forceinline__ float bf2f(unsigned short u) {
  return __builtin_bit_cast(float, ((unsigned int)u) << 16);
}
static __device__ __forceinline__ unsigned int fbits(float f) {
  return __builtin_bit_cast(unsigned int, f);
}

typedef const __attribute__((address_space(1))) unsigned int* gp1_t;
typedef __attribute__((address_space(3))) unsigned int* lp3_t;
static __device__ __forceinline__ void gl_lds16(const void* g, void* l) {
  __builtin_amdgcn_global_load_lds((gp1_t)g, (lp3_t)l, 16, 0, 0);
}

// ---------------------------------------------------------------------------
// Kernel 0: W fp32 -> Wf FRAGMENT-READY bf16 (unchanged from round 7).
// ---------------------------------------------------------------------------
__global__ __launch_bounds__(256) void conv_w(const float* __restrict__ wq,
    const float* __restrict__ wk, const float* __restrict__ wv,
    unsigned short* __restrict__ wf) {
  int c = blockIdx.x * 256 + threadIdx.x;   // 24576 chunks
  int lane = c & 63;
  int t = c >> 6;
  int ng = t % 12;
  int kk = t / 12;                           // kt*2+ks, 0..31
  int k0 = kk * 32 + (lane >> 4) * 8;
  int n = ng * 16 + (lane & 15);
  const float* src;
  int col;
  float scale = 1.0f;
  if (n < 64)       { src = wq; col = n;       scale = 0.03125f * 1.44269504088896340736f; }
  else if (n < 128) { src = wk; col = n - 64;  }
  else              { src = wv; col = n - 128; }
  unsigned short o[8];
#pragma unroll
  for (int j = 0; j < 8; ++j) o[j] = f2bf(src[(size_t)(k0 + j) * H_ + col] * scale);
  *(uint4*)&wf[(size_t)c * 8] = *(const uint4*)o;
}

// ---------------------------------------------------------------------------
// Kernel 1: QKV projection, SUPER-STEPPED async-LDS GEMM.
// Grid 512 (32-row tiles), 4 waves. x: 4 LDS buffers (32 KB), barrier every
// TWO k-tiles -- stages issued at super-step start get a ~2x compute window
// before the barrier's vmcnt(0) drain. W: direct frag loads from Wf, with
// sched_group_barrier forcing all 12 per-super-step W loads to issue as a
// group ahead of the ds_reads/MFMAs (defeats the compiler's load-sinking
// that serialized ~6 L2 latencies per tile in rounds 2-7).
// Epilogue emits q direct and K/V fragment-ready (unchanged).
// ---------------------------------------------------------------------------
__global__ __launch_bounds__(256) void qkv_proj(
    const float* __restrict__ x, const unsigned short* __restrict__ wf,
    unsigned short* __restrict__ qo, unsigned short* __restrict__ kf,
    unsigned short* __restrict__ vf) {
  __shared__ float XL[4][2048];            // 4 x 32x64 fp32 = 32 KB
  int tid = threadIdx.x;
  int wave = tid >> 6, lane = tid & 63;
  int lane4 = lane & 15, quad = lane >> 4;
  int m0 = blockIdx.x * 32;

  floatx4 acc[2][3];
#pragma unroll
  for (int mt = 0; mt < 2; ++mt)
#pragma unroll
    for (int nt = 0; nt < 3; ++nt) acc[mt][nt] = (floatx4)0.0f;

  // stage one 32x64 x-tile (fp32) into buffer `buf`, XOR-swizzled chunks
  auto stage_tile = [&](int kt, int buf) {
    int k0 = kt * 64;
#pragma unroll
    for (int j = 0; j < 2; ++j) {
      int p = (wave * 2 + j) * 64 + lane;
      int r = p >> 4, pc = p & 15;
      int cl = (pc & 8) | ((pc ^ (r & 7)) & 7);
      gl_lds16(&x[(size_t)(m0 + r) * C_ + k0 + cl * 4], &XL[buf][(wave * 2 + j) * 256]);
    }
  };

  stage_tile(0, 0);
  stage_tile(1, 1);
  __syncthreads();

  for (int ss = 0; ss < 8; ++ss) {
    int t0 = 2 * ss;
    if (ss < 7) {                       // prefetch the NEXT super-step's pair
      stage_tile(t0 + 2, (t0 + 2) & 3);
      stage_tile(t0 + 3, (t0 + 3) & 3);
    }
#pragma unroll
    for (int tt = 0; tt < 2; ++tt) {
      int kt = t0 + tt, buf = kt & 3;
#pragma unroll
      for (int ks = 0; ks < 2; ++ks) {
        short8 b[3];
#pragma unroll
        for (int nt = 0; nt < 3; ++nt)
          b[nt] = *(const short8*)&wf[(size_t)(((kt * 2 + ks) * 12) + wave * 3 + nt) * 512 + lane * 8];
        short8 a[2];
#pragma unroll
        for (int mt = 0; mt < 2; ++mt) {
          int r = mt * 16 + lane4;
          int cl0 = ks * 8 + quad * 2;
          int pc0 = (cl0 & 8) | ((cl0 ^ (r & 7)) & 7);
          int pc1 = ((cl0 + 1) & 8) | (((cl0 + 1) ^ (r & 7)) & 7);
          float4 f0 = *(const float4*)&XL[buf][r * 64 + pc0 * 4];
          float4 f1 = *(const float4*)&XL[buf][r * 64 + pc1 * 4];
          intx4 pk;
          pk[0] = (int)__builtin_amdgcn_perm(fbits(f0.y), fbits(f0.x), 0x07060302u);
          pk[1] = (int)__builtin_amdgcn_perm(fbits(f0.w), fbits(f0.z), 0x07060302u);
          pk[2] = (int)__builtin_amdgcn_perm(fbits(f1.y), fbits(f1.x), 0x07060302u);
          pk[3] = (int)__builtin_amdgcn_perm(fbits(f1.w), fbits(f1.z), 0x07060302u);
          a[mt] = __builtin_bit_cast(short8, pk);
        }
#pragma unroll
        for (int mt = 0; mt < 2; ++mt)
#pragma unroll
          for (int nt = 0; nt < 3; ++nt)
            acc[mt][nt] = __builtin_amdgcn_mfma_f32_16x16x32_bf16(a[mt], b[nt], acc[mt][nt], 0, 0, 0);
      }
    }
    // scheduling pipeline for the super-step's compute region:
    // all 12 W vmem-reads first, then the 16 ds_reads, then the 24 MFMAs.
    __builtin_amdgcn_sched_group_barrier(0x020, 12, 0);   // VMEM read
    __builtin_amdgcn_sched_group_barrier(0x100, 16, 0);   // DS read
    __builtin_amdgcn_sched_group_barrier(0x008, 24, 0);   // MFMA
    __syncthreads();
  }

  // ---- epilogue: q direct; K,V via LDS into fragment-ready layouts ----
  unsigned short* VTB = (unsigned short*)&XL[0][0];   // [64 h][40] bf16 (V^T)
  unsigned short* KB  = VTB + 5120;                   // [32 t][72] bf16
#pragma unroll
  for (int mt = 0; mt < 2; ++mt)
#pragma unroll
    for (int nt = 0; nt < 3; ++nt) {
      int n = wave * 48 + nt * 16 + lane4;
#pragma unroll
      for (int rr = 0; rr < 4; ++rr) {
        unsigned short val = f2bf(acc[mt][nt][rr]);
        int lrow = mt * 16 + quad * 4 + rr;
        if (n < 64)       qo[(size_t)(m0 + lrow) * H_ + n] = val;
        else if (n < 128) KB[lrow * 72 + (n - 64)] = val;
        else              VTB[(n - 128) * 40 + lrow] = val;
      }
    }
  __syncthreads();
  {
    int bb = m0 >> 11, t0 = m0 & 2047;
    int st = t0 >> 6, off = t0 & 63;
    // K: 256 chunks (ks x ctl x 64 lanes)
    int ks = tid >> 7, ctl = (tid >> 6) & 1, ln = tid & 63;
    int ct = (off >> 4) + ctl;
    int tl = ctl * 16 + (ln & 15);
    int h0 = ks * 32 + (ln >> 4) * 8;
    uint4 kd = *(const uint4*)&KB[tl * 72 + h0];
    *(uint4*)&kf[((size_t)((bb * 32 + st) * 2 + ks) * 4 + ct) * 512 + ln * 8] = kd;
    // V: 256 chunks (nt x 64 lanes), ks fixed = off>>5
    int nt = tid >> 6, l4 = tid & 15, qs = (tid >> 4) & 3;
    int ksv = off >> 5;
    uint4 vd = *(const uint4*)&VTB[(nt * 16 + l4) * 40 + qs * 8];
    *(uint4*)&vf[((size_t)((bb * 32 + st) * 2 + ksv) * 4 + nt) * 512 + (tid & 63) * 8] = vd;
  }
}

// ---------------------------------------------------------------------------
// Kernel 2: causal flash attention, barrier-free, split-4, fixed-max softmax
// (m=8, base-2 scale folded into Wq). Unchanged from round 7.
// ---------------------------------------------------------------------------
__global__ __launch_bounds__(256) void attn(
    const unsigned short* __restrict__ qi, const unsigned short* __restrict__ Kf,
    const unsigned short* __restrict__ Vf, unsigned short* __restrict__ Op,
    float* __restrict__ lsum) {
  __shared__ unsigned short PL[4][16][72];

  int tid = threadIdx.x;
  int wave = tid >> 6, lane = tid & 63;
  int lane4 = lane & 15, quad = lane >> 4;
  int qt = 31 - (int)blockIdx.x;   // biggest blocks dispatch first
  int b = blockIdx.y, split = blockIdx.z;
  int qb = qt * 64;
  int base = b * T_;

  int ntile = qt + 1;
  int sBeg = (split * ntile) >> 2;
  int sEnd = ((split + 1) * ntile) >> 2;

  short8 aq[2];
#pragma unroll
  for (int ks = 0; ks < 2; ++ks)
    aq[ks] = *(const short8*)&qi[(size_t)(base + qb + wave * 16 + lane4) * H_ + ks * 32 + quad * 8];

  float lrow[4];
  floatx4 o[4];
#pragma unroll
  for (int r = 0; r < 4; ++r) lrow[r] = 0.0f;
#pragma unroll
  for (int nt = 0; nt < 4; ++nt) o[nt] = (floatx4)0.0f;

  for (int st = sBeg; st < sEnd; ++st) {
    size_t tb = (size_t)(b * 32 + st) * 8;
    short8 bk[2][4], bv[2][4];
#pragma unroll
    for (int ks = 0; ks < 2; ++ks)
#pragma unroll
      for (int ct = 0; ct < 4; ++ct)
        bk[ks][ct] = *(const short8*)&Kf[(tb + ks * 4 + ct) * 512 + lane * 8];
#pragma unroll
    for (int ks = 0; ks < 2; ++ks)
#pragma unroll
      for (int nt = 0; nt < 4; ++nt)
        bv[ks][nt] = *(const short8*)&Vf[(tb + ks * 4 + nt) * 512 + lane * 8];

    floatx4 sacc[4];
#pragma unroll
    for (int ct = 0; ct < 4; ++ct) sacc[ct] = (floatx4)0.0f;
#pragma unroll
    for (int ks = 0; ks < 2; ++ks)
#pragma unroll
      for (int ct = 0; ct < 4; ++ct)
        sacc[ct] = __builtin_amdgcn_mfma_f32_16x16x32_bf16(aq[ks], bk[ks][ct], sacc[ct], 0, 0, 0);

    if (st == qt) {   // diagonal tile mask
#pragma unroll
      for (int ct = 0; ct < 4; ++ct)
#pragma unroll
        for (int r = 0; r < 4; ++r) {
          int qrow = wave * 16 + quad * 4 + r;
          int scol = ct * 16 + lane4;
          if (scol > qrow) sacc[ct][r] = -3.0e38f;
        }
    }

    // fixed-max softmax: p = exp2(s - 8)
#pragma unroll
    for (int ct = 0; ct < 4; ++ct)
#pragma unroll
      for (int r = 0; r < 4; ++r) {
        float p = exp2f(sacc[ct][r] - 8.0f);
        lrow[r] += p;
        PL[wave][quad * 4 + r][ct * 16 + lane4] = f2bf_t(p);
      }

    // O += P V  (PL write->read same-wave; lgkmcnt orders it)
#pragma unroll
    for (int ks = 0; ks < 2; ++ks) {
      short8 pa = *(const short8*)&PL[wave][lane4][ks * 32 + quad * 8];
#pragma unroll
      for (int nt = 0; nt < 4; ++nt)
        o[nt] = __builtin_amdgcn_mfma_f32_16x16x32_bf16(pa, bv[ks][nt], o[nt], 0, 0, 0);
    }
  }

  // epilogue: l-reduce across the 16 lanes of each quad-group
#pragma unroll
  for (int off = 1; off < 16; off <<= 1)
#pragma unroll
    for (int r = 0; r < 4; ++r) lrow[r] += __shfl_xor(lrow[r], off);

  size_t pbase = (((size_t)split * 8 + b) * 32 + qt) * 64;
#pragma unroll
  for (int r = 0; r < 4; ++r) {
    int row = wave * 16 + quad * 4 + r;
#pragma unroll
    for (int nt = 0; nt < 4; ++nt)
      Op[(pbase + row) * 64 + nt * 16 + lane4] = f2bf(o[nt][r]);
    if (lane4 == 0) lsum[pbase + row] = lrow[r];
  }
}

// ---------------------------------------------------------------------------
// Kernel 3: merge the 4 key-range splits: out = sum(O_i) / sum(l_i).
// ---------------------------------------------------------------------------
__global__ __launch_bounds__(256) void merge_splits(
    const unsigned short* __restrict__ Op, const float* __restrict__ lsum,
    float* __restrict__ out) {
  int idx = blockIdx.x * 256 + threadIdx.x;
  int row = idx >> 4;
  int h4 = (idx & 15) * 4;
  int b = row >> 11, t = row & 2047;
  int qt = t >> 6, r = t & 63;
  float O0 = 0.f, O1 = 0.f, O2 = 0.f, O3 = 0.f, l = 0.f;
#pragma unroll
  for (int s = 0; s < 4; ++s) {
    size_t p = (((size_t)s * 8 + b) * 32 + qt) * 64 + r;
    l += lsum[p];
    ushort4 ov = *(const ushort4*)&Op[p * 64 + h4];
    O0 += bf2f(ov.x); O1 += bf2f(ov.y); O2 += bf2f(ov.z); O3 += bf2f(ov.w);
  }
  float inv = 1.0f / l;
  float4 res = make_float4(O0 * inv, O1 * inv, O2 * inv, O3 * inv);
  *(float4*)&out[(size_t)row * H_ + h4] = res;
}

extern "C" void kernel_launch(void* const* d_in, const int* in_sizes, int n_in,
                              void* d_out, int out_size, void* d_ws, size_t ws_size,
                              hipStream_t stream) {
  const float* x  = (const float*)d_in[0];
  const float* wq = (const float*)d_in[1];
  const float* wk = (const float*)d_in[2];
  const float* wv = (const float*)d_in[3];
  float* out = (float*)d_out;

  char* ws = (char*)d_ws;
  unsigned short* wf = (unsigned short*)ws;                    // 393216 B
  unsigned short* qb = (unsigned short*)(ws + 393216);         // 2097152 B
  unsigned short* kf = (unsigned short*)(ws + 2490368);        // 2097152 B (frag-ready)
  unsigned short* vf = (unsigned short*)(ws + 4587520);        // 2097152 B (frag-ready)
  unsigned short* Op = (unsigned short*)(ws + 6684672);        // 8388608 B (4 splits)
  float*          ls = (float*)(ws + 15073280);                // 262144 B (total 15335424)

  conv_w<<<96, 256, 0, stream>>>(wq, wk, wv, wf);
  qkv_proj<<<512, 256, 0, stream>>>(x, wf, qb, kf, vf);
  attn<<<dim3(32, 8, 4), 256, 0, stream>>>(qb, kf, vf, Op, ls);
  merge_splits<<<1024, 256, 0, stream>>>(Op, ls, out);
}